// Round 4
// baseline (486.286 us; speedup 1.0000x reference)
//
#include <hip/hip_runtime.h>
#include <stdint.h>

#define NCLS  21
#define CDIM  256
#define HWSZ  16384
#define NPIX  131072
#define EPSV  1e-6f
#define NEGV  -1e30f
#define CAP_W 4096
#define CAP_S 16384
#define KSEL  256
#define NCC   16           // channel chunks in k1a
#define CCH   (CDIM/NCC)   // 16 channels per chunk
#define NPART 8            // strong top-k partitions per class
#define NWP   8            // wsum pixel partitions per class
#define NBLK  (NPIX/1024)  // 128 pixel groups (1024 pixels each)

__device__ __forceinline__ uint64_t pack_key(float v, unsigned idx) {
  unsigned u = __float_as_uint(v);
  u = (u & 0x80000000u) ? ~u : (u | 0x80000000u);  // order-preserving map
  return ((uint64_t)(~u) << 32) | (uint64_t)idx;   // ascending key == descending value, tie -> low idx
}

// ---------------- K0: normalize prototypes, zero accumulators ----------------
__global__ void k0_init(const float* __restrict__ mb, float* pn, float* wsum) {
  int k = blockIdx.x, t = threadIdx.x;
  float v = mb[k * CDIM + t];
  float s = v * v;
  for (int o = 32; o > 0; o >>= 1) s += __shfl_down(s, o, 64);
  __shared__ float wsh[4];
  int wid = t >> 6, lane = t & 63;
  if (lane == 0) wsh[wid] = s;
  __syncthreads();
  float tot = wsh[0] + wsh[1] + wsh[2] + wsh[3];
  float inv = 1.0f / fmaxf(sqrtf(tot), EPSV);
  pn[k * CDIM + t] = v * inv;
  wsum[k * CDIM + t] = 0.0f;
}

// ---------------- KC: per-block class histograms (strong/weak counts) ----------------
__global__ void kcount(const int* __restrict__ seg, const int* __restrict__ ign,
                       const float* __restrict__ prob, int* cnts) {
  __shared__ int hs[NCLS], hw2[NCLS];
  int t = threadIdx.x, pg = blockIdx.x;
  if (t < NCLS) { hs[t] = 0; hw2[t] = 0; }
  __syncthreads();
  int n0 = pg * 1024 + t * 4;
  int4   sg = *(const int4*)(seg + n0);
  int4   ig = *(const int4*)(ign + n0);
  float4 pr = *(const float4*)(prob + n0);
  if (ig.x != 255) { atomicAdd(&hs[sg.x], 1); if (pr.x > 0.95f) atomicAdd(&hw2[sg.x], 1); }
  if (ig.y != 255) { atomicAdd(&hs[sg.y], 1); if (pr.y > 0.95f) atomicAdd(&hw2[sg.y], 1); }
  if (ig.z != 255) { atomicAdd(&hs[sg.z], 1); if (pr.z > 0.95f) atomicAdd(&hw2[sg.z], 1); }
  if (ig.w != 255) { atomicAdd(&hs[sg.w], 1); if (pr.w > 0.95f) atomicAdd(&hw2[sg.w], 1); }
  __syncthreads();
  if (t < NCLS) {
    cnts[pg * NCLS + t] = hs[t];
    cnts[NBLK * NCLS + pg * NCLS + t] = hw2[t];
  }
}

// ---------------- K1a: pure streaming pass — float4 loads, partial dots ----------------
// grid: (NBLK, NCC). Each thread: 4 pixels, CCH channels. No atomics, no branches.
__global__ void k1a_stream(const float* __restrict__ fw, const float* __restrict__ fs,
                           const int* __restrict__ seg, const float* __restrict__ pn,
                           float* part) {
  __shared__ float pnT[CCH * NCLS];  // [c_local][k]
  int t = threadIdx.x;
  int pg = blockIdx.x;   // pixel group (1024 pixels)
  int cc = blockIdx.y;   // channel chunk
  int c0 = cc * CCH;
  for (int i = t; i < CCH * NCLS; i += 256) {
    int c = i / NCLS, k = i % NCLS;
    pnT[i] = pn[k * CDIM + c0 + c];
  }
  __syncthreads();

  int n0 = pg * 1024 + t * 4;
  int b = n0 >> 14, hw = n0 & (HWSZ - 1);
  int4 sg = *(const int4*)(seg + n0);

  const float* fwp = fw + ((size_t)b * CDIM + c0) * HWSZ + hw;
  const float* fsp = fs + ((size_t)b * CDIM + c0) * HWSZ + hw;

  float4 dw = {0,0,0,0}, nw = {0,0,0,0}, dsv = {0,0,0,0}, ns = {0,0,0,0};
#pragma unroll
  for (int cl = 0; cl < CCH; ++cl) {
    float4 a = *(const float4*)(fwp + (size_t)cl * HWSZ);
    float4 s = *(const float4*)(fsp + (size_t)cl * HWSZ);
    float p0 = pnT[cl * NCLS + sg.x];
    float p1 = pnT[cl * NCLS + sg.y];
    float p2 = pnT[cl * NCLS + sg.z];
    float p3 = pnT[cl * NCLS + sg.w];
    dw.x = fmaf(a.x, p0, dw.x); nw.x = fmaf(a.x, a.x, nw.x);
    dw.y = fmaf(a.y, p1, dw.y); nw.y = fmaf(a.y, a.y, nw.y);
    dw.z = fmaf(a.z, p2, dw.z); nw.z = fmaf(a.z, a.z, nw.z);
    dw.w = fmaf(a.w, p3, dw.w); nw.w = fmaf(a.w, a.w, nw.w);
    dsv.x = fmaf(s.x, p0, dsv.x); ns.x = fmaf(s.x, s.x, ns.x);
    dsv.y = fmaf(s.y, p1, dsv.y); ns.y = fmaf(s.y, s.y, ns.y);
    dsv.z = fmaf(s.z, p2, dsv.z); ns.z = fmaf(s.z, s.z, ns.z);
    dsv.w = fmaf(s.w, p3, dsv.w); ns.w = fmaf(s.w, s.w, ns.w);
  }
  float4* pp = (float4*)part + ((size_t)cc * NPIX + n0);
  pp[0] = make_float4(dw.x, nw.x, dsv.x, ns.x);
  pp[1] = make_float4(dw.y, nw.y, dsv.y, ns.y);
  pp[2] = make_float4(dw.z, nw.z, dsv.z, ns.z);
  pp[3] = make_float4(dw.w, nw.w, dsv.w, ns.w);
}

// ---------------- KS: exclusive scan of per-block class counts ----------------
__global__ void ks_scan(const int* __restrict__ cnts, int* offs, int* scnt, int* wcnt) {
  __shared__ int L[2 * NBLK * NCLS];
  int t = threadIdx.x;
  for (int i = t; i < 2 * NBLK * NCLS; i += 256) L[i] = cnts[i];
  __syncthreads();
  if (t < 2 * NCLS) {
    int q = t % NCLS;
    int typ = t / NCLS;  // 0 strong, 1 weak
    int base = typ * NBLK * NCLS;
    int run = 0;
    for (int b2 = 0; b2 < NBLK; ++b2) {
      int v = L[base + b2 * NCLS + q];
      L[base + b2 * NCLS + q] = run;
      run += v;
    }
    if (typ == 0) scnt[q] = run; else wcnt[q] = run;
  }
  __syncthreads();
  for (int i = t; i < 2 * NBLK * NCLS; i += 256) offs[i] = L[i];
}

// ---------------- K1b: combine partials, compute sims, write keys at precomputed offsets ----------------
__global__ void k1b_write(const float* __restrict__ part, const float* __restrict__ prob,
                          const int* __restrict__ seg, const int* __restrict__ ign,
                          const int* __restrict__ offs, uint64_t* wkeys, uint64_t* skeys) {
  __shared__ int ls[NCLS], lw[NCLS];
  int t = threadIdx.x, pg = blockIdx.x;
  if (t < NCLS) {
    ls[t] = offs[pg * NCLS + t];
    lw[t] = offs[NBLK * NCLS + pg * NCLS + t];
  }
  __syncthreads();
  int n0 = pg * 1024 + t * 4;
  int4   sg = *(const int4*)(seg + n0);
  int4   ig = *(const int4*)(ign + n0);
  float4 pr = *(const float4*)(prob + n0);
  float dw[4] = {0,0,0,0}, nw[4] = {0,0,0,0}, ds[4] = {0,0,0,0}, ns[4] = {0,0,0,0};
#pragma unroll
  for (int cc = 0; cc < NCC; ++cc) {
    const float4* pp = (const float4*)part + ((size_t)cc * NPIX + n0);
#pragma unroll
    for (int i = 0; i < 4; ++i) {
      float4 v = pp[i];
      dw[i] += v.x; nw[i] += v.y; ds[i] += v.z; ns[i] += v.w;
    }
  }
  int   sga[4] = {sg.x, sg.y, sg.z, sg.w};
  int   iga[4] = {ig.x, ig.y, ig.z, ig.w};
  float pra[4] = {pr.x, pr.y, pr.z, pr.w};
#pragma unroll
  for (int i = 0; i < 4; ++i) {
    if (iga[i] != 255) {
      int q = sga[i];
      float sim_s = ds[i] / fmaxf(sqrtf(ns[i]), EPSV);
      int pos = atomicAdd(&ls[q], 1);
      if (pos < CAP_S) skeys[(size_t)q * CAP_S + pos] = pack_key(-sim_s, (unsigned)(n0 + i));
      if (pra[i] > 0.95f) {
        float sim_w = dw[i] / fmaxf(sqrtf(nw[i]), EPSV);
        int pw = atomicAdd(&lw[q], 1);
        if (pw < CAP_W) wkeys[(size_t)q * CAP_W + pw] = pack_key(sim_w, (unsigned)(n0 + i));
      }
    }
  }
}

// ---------------- KW: wsum via weak-candidate list replay ----------------
__global__ void kwsum(const float* __restrict__ fw, const uint64_t* __restrict__ wkeys,
                      const int* __restrict__ wcnt, float* wsum) {
  int q = blockIdx.x, p = blockIdx.y, t = threadIdx.x;
  int cnt = min(wcnt[q], CAP_W);
  int chunk = (cnt + NWP - 1) / NWP;
  int lo = p * chunk, hi = min(lo + chunk, cnt);
  float acc = 0.0f;
  for (int i = lo; i < hi; ++i) {
    unsigned n = (unsigned)(wkeys[(size_t)q * CAP_W + i] & 0xFFFFFFFFull);
    int b = (int)(n >> 14), hw = (int)(n & (HWSZ - 1));
    acc += fw[((size_t)b * CDIM + t) * HWSZ + hw];
  }
  if (hi > lo) atomicAdd(&wsum[q * CDIM + t], acc);
}

// ---------------- top-256 select (cutoff-filtered bitonic), 256 threads ----------------
__device__ void select_topk(const uint64_t* __restrict__ list, int cnt,
                            uint64_t* T, uint64_t* P, int* pcnt, int* woff) {
  int t = threadIdx.x;
  T[t] = ~0ull;
  if (t == 0) *pcnt = 0;
  __syncthreads();
  for (int base = 0; base < cnt; base += 256) {
    uint64_t key = (base + t < cnt) ? list[base + t] : ~0ull;
    uint64_t cutoff = T[KSEL - 1];
    bool pred = key < cutoff;
    unsigned long long mask = __ballot(pred);
    int wid = t >> 6, lane = t & 63;
    if (lane == 0) woff[wid] = __popcll(mask);
    int prefix = __popcll(mask & ((1ull << lane) - 1ull));
    __syncthreads();
    int off = 0;
    for (int w2 = 0; w2 < wid; ++w2) off += woff[w2];
    int total = woff[0] + woff[1] + woff[2] + woff[3];
    int old = *pcnt;
    if (pred) P[old + off + prefix] = key;
    int newc = old + total;
    __syncthreads();
    if (t == 0) *pcnt = newc;
    bool last = (base + 256 >= cnt);
    if (newc >= KSEL || (last && newc > 0)) {
      for (int i2 = t; i2 < 2 * KSEL; i2 += 256)
        if (i2 >= newc) P[i2] = ~0ull;
      for (unsigned size = 2; size <= 2 * KSEL; size <<= 1) {
        for (unsigned stride = size >> 1; stride > 0; stride >>= 1) {
          __syncthreads();
          unsigned lo = stride - 1;
          unsigned i = (((unsigned)t & ~lo) << 1) | ((unsigned)t & lo);
          unsigned j = i | stride;
          uint64_t a = P[i], b = P[j];
          bool up = ((i & size) == 0);
          if ((a > b) == up) { P[i] = b; P[j] = a; }
        }
      }
      __syncthreads();
      uint64_t a = T[t], b = P[KSEL - 1 - t];
      T[t] = a < b ? a : b;
      for (unsigned stride = KSEL / 2; stride > 0; stride >>= 1) {
        __syncthreads();
        if (((unsigned)t & stride) == 0) {
          uint64_t x = T[t], y = T[t + stride];
          if (x > y) { T[t] = y; T[t + stride] = x; }
        }
      }
      __syncthreads();
      if (t == 0) *pcnt = 0;
      __syncthreads();
    } else {
      __syncthreads();
    }
  }
}

// ---------------- K2: weak top-16 (full) + strong top-256 (partitioned) ----------------
__global__ void k2_topk(const uint64_t* __restrict__ wkeys, const uint64_t* __restrict__ skeys,
                        const int* wcnt, const int* scnt,
                        uint64_t* psel, int* idxw, int* kwv, int* nwv) {
  __shared__ uint64_t T[KSEL];
  __shared__ uint64_t P[2 * KSEL];
  __shared__ int pcnt;
  __shared__ int woff[4];
  int bid = blockIdx.x, t = threadIdx.x;
  if (bid < NCLS * NPART) {
    int k = bid / NPART, p = bid % NPART;
    int cnt = min(scnt[k], CAP_S);
    int chunk = (cnt + NPART - 1) / NPART;
    int lo = p * chunk;
    int hi = min(lo + chunk, cnt);
    int c = hi > lo ? hi - lo : 0;
    select_topk(skeys + (size_t)k * CAP_S + lo, c, T, P, &pcnt, woff);
    psel[((size_t)k * NPART + p) * KSEL + t] = T[t];
  } else {
    int k = bid - NCLS * NPART;
    int cnt_total = wcnt[k];
    int cnt = min(cnt_total, CAP_W);
    select_topk(wkeys + (size_t)k * CAP_W, cnt, T, P, &pcnt, woff);
    if (t < 16) idxw[k * 16 + t] = (int)(unsigned)(T[t] & 0xFFFFFFFFull);
    if (t == 0) { nwv[k] = cnt_total; kwv[k] = min(cnt_total, 16); }
  }
}

// ---------------- K2m: merge 8 sorted partition results -> final strong top-256 ----------------
__global__ void k2m_merge(const uint64_t* __restrict__ psel, const int* scnt,
                          int* idxs, int* ksv, int* nsv) {
  int k = blockIdx.x, t = threadIdx.x;
  __shared__ uint64_t M[NPART * KSEL];  // 2048
  for (int i = t; i < NPART * KSEL; i += 256) M[i] = psel[(size_t)k * NPART * KSEL + i];
  for (unsigned size = 2; size <= NPART * KSEL; size <<= 1) {
    for (unsigned stride = size >> 1; stride > 0; stride >>= 1) {
      __syncthreads();
      for (unsigned q = t; q < NPART * KSEL / 2; q += 256) {
        unsigned lo = stride - 1;
        unsigned i = ((q & ~lo) << 1) | (q & lo);
        unsigned j = i | stride;
        uint64_t a = M[i], b = M[j];
        bool up = ((i & size) == 0);
        if ((a > b) == up) { M[i] = b; M[j] = a; }
      }
    }
  }
  __syncthreads();
  idxs[k * KSEL + t] = (int)(unsigned)(M[t] & 0xFFFFFFFFull);
  if (t == 0) { int c = scnt[k]; nsv[k] = c; ksv[k] = c < KSEL ? c : KSEL; }
}

// ---------------- K3a: gather + normalize selected vectors into dense buffers ----------------
__global__ void k3a_gather(const float* __restrict__ fw, const float* __restrict__ fs,
                           const int* __restrict__ idxw, const int* __restrict__ idxs,
                           const int* __restrict__ kwv, const int* __restrict__ ksv,
                           float* dw_dense, float* ds_dense) {
  int k = blockIdx.y;
  int slot = blockIdx.x;  // 0..255 strong, 256..271 weak
  int t = threadIdx.x;
  bool strong = slot < KSEL;
  float v = 0.0f;
  int n = 0;
  bool ok;
  if (strong) {
    ok = slot < ksv[k];
    if (ok) n = idxs[k * KSEL + slot];
  } else {
    int i = slot - KSEL;
    ok = i < kwv[k];
    int rank = i > 0 ? i - 1 : 0;  // ranks = max(arange(16)-1, 0)
    if (ok) n = idxw[k * 16 + rank];
  }
  if (ok) {
    int b = n >> 14, hw = n & (HWSZ - 1);
    const float* f = strong ? fs : fw;
    v = f[(size_t)(b * CDIM + t) * HWSZ + hw];
  }
  float s = v * v;
  for (int o = 32; o > 0; o >>= 1) s += __shfl_down(s, o, 64);
  __shared__ float wsh[4];
  int wid = t >> 6, lane = t & 63;
  if (lane == 0) wsh[wid] = s;
  __syncthreads();
  float tot = wsh[0] + wsh[1] + wsh[2] + wsh[3];
  float inv = 1.0f / fmaxf(sqrtf(tot), EPSV);
  float out = v * inv;
  if (strong) ds_dense[((size_t)k * KSEL + slot) * CDIM + t] = out;
  else        dw_dense[((size_t)k * 16 + (slot - KSEL)) * CDIM + t] = out;
}

// ---------------- K3b: cosm, per-row max, per-class sum ----------------
__global__ void k3b_loss(const float* __restrict__ dw_dense, const float* __restrict__ ds_dense,
                         const int* kwv, const int* ksv, const int* nwv, const int* nsv,
                         float* simsum, int* countk) {
  int k = blockIdx.x, t = threadIdx.x;
  int wid = t >> 6, lane = t & 63;
  __shared__ float wn[16 * CDIM];
  __shared__ float wred[4][16];
  for (int i = t; i < 16 * CDIM; i += 256) wn[i] = dw_dense[(size_t)k * 16 * CDIM + i];
  __syncthreads();
  int ks_ = ksv[k], kw_ = kwv[k];
  bool ok = (nwv[k] > 0) && (nsv[k] > 0);
  float dots[16];
#pragma unroll
  for (int i = 0; i < 16; ++i) dots[i] = 0.0f;
  bool jv = ok && (t < ks_);
  if (jv) {
    const float4* sp = (const float4*)(ds_dense + ((size_t)k * KSEL + t) * CDIM);
    for (int c4 = 0; c4 < CDIM / 4; ++c4) {
      float4 v = sp[c4];
#pragma unroll
      for (int i = 0; i < 16; ++i) {
        float4 w = ((const float4*)(wn + i * CDIM))[c4];
        dots[i] = fmaf(v.x, w.x, dots[i]);
        dots[i] = fmaf(v.y, w.y, dots[i]);
        dots[i] = fmaf(v.z, w.z, dots[i]);
        dots[i] = fmaf(v.w, w.w, dots[i]);
      }
    }
  }
#pragma unroll
  for (int i = 0; i < 16; ++i) {
    float v = jv ? dots[i] : NEGV;
    for (int o = 32; o > 0; o >>= 1) v = fmaxf(v, __shfl_down(v, o, 64));
    if (lane == 0) wred[wid][i] = v;
  }
  __syncthreads();
  if (t == 0) {
    float csum = 0.0f;
    for (int i = 0; i < kw_; ++i) {
      float m = fmaxf(fmaxf(wred[0][i], wred[1][i]), fmaxf(wred[2][i], wred[3][i]));
      csum += m;
    }
    simsum[k] = ok ? csum : 0.0f;
    countk[k] = ok ? ks_ : 0;
  }
}

// ---------------- K4: memory bank update + loss ----------------
__global__ void k4_final(const float* __restrict__ mb, const float* __restrict__ wsum,
                         const int* __restrict__ nwv, const float* __restrict__ simsum,
                         const int* __restrict__ countk, float* out) {
  int k = blockIdx.x, t = threadIdx.x;
  float p = mb[k * CDIM + t];
  float o = p;
  int nw = nwv[k];
  if (nw > 0) {
    float mean = wsum[k * CDIM + t] / (float)nw;
    o = 0.99f * p + 0.01f * mean;
  }
  out[1 + k * CDIM + t] = o;
  if (k == 0 && t == 0) {
    float ss = 0.0f;
    int cc = 0;
    for (int q = 0; q < NCLS; ++q) { ss += simsum[q]; cc += countk[q]; }
    out[0] = (cc > 0) ? (1.0f - ss / (float)cc) : 0.0f;
  }
}

extern "C" void kernel_launch(void* const* d_in, const int* in_sizes, int n_in,
                              void* d_out, int out_size, void* d_ws, size_t ws_size,
                              hipStream_t stream) {
  const float* fw   = (const float*)d_in[0];
  const float* fs   = (const float*)d_in[1];
  const float* prob = (const float*)d_in[2];
  const float* mb   = (const float*)d_in[3];
  const int*   seg  = (const int*)d_in[4];
  const int*   ign  = (const int*)d_in[5];
  float* out = (float*)d_out;

  char* ws = (char*)d_ws;
  size_t off = 0;
  auto alloc = [&](size_t bytes) -> char* {
    char* p = ws + off;
    off = (off + bytes + 255) & ~(size_t)255;
    return p;
  };
  float*    pn       = (float*)alloc(NCLS * CDIM * 4);
  float*    wsum     = (float*)alloc(NCLS * CDIM * 4);
  int*      wcnt     = (int*)alloc(NCLS * 4);
  int*      scnt     = (int*)alloc(NCLS * 4);
  int*      idxw     = (int*)alloc(NCLS * 16 * 4);
  int*      idxs     = (int*)alloc(NCLS * KSEL * 4);
  int*      kwv      = (int*)alloc(NCLS * 4);
  int*      ksv      = (int*)alloc(NCLS * 4);
  int*      nwv      = (int*)alloc(NCLS * 4);
  int*      nsv      = (int*)alloc(NCLS * 4);
  float*    simsum   = (float*)alloc(NCLS * 4);
  int*      countk   = (int*)alloc(NCLS * 4);
  int*      cnts     = (int*)alloc(2 * NBLK * NCLS * 4);
  int*      offs     = (int*)alloc(2 * NBLK * NCLS * 4);
  uint64_t* wkeys    = (uint64_t*)alloc((size_t)NCLS * CAP_W * 8);
  uint64_t* skeys    = (uint64_t*)alloc((size_t)NCLS * CAP_S * 8);
  uint64_t* psel     = (uint64_t*)alloc((size_t)NCLS * NPART * KSEL * 8);
  float*    part     = (float*)alloc((size_t)NCC * NPIX * 4 * 4);  // 33.5 MB
  // dense buffers alias part: part fully consumed by k1b before k3a writes these
  float*    dw_dense = part;
  float*    ds_dense = part + (size_t)NCLS * 16 * CDIM;
  (void)in_sizes; (void)n_in; (void)out_size; (void)ws_size;

  k0_init<<<NCLS, 256, 0, stream>>>(mb, pn, wsum);
  kcount<<<NBLK, 256, 0, stream>>>(seg, ign, prob, cnts);
  ks_scan<<<1, 256, 0, stream>>>(cnts, offs, scnt, wcnt);
  k1a_stream<<<dim3(NBLK, NCC), 256, 0, stream>>>(fw, fs, seg, pn, part);
  k1b_write<<<NBLK, 256, 0, stream>>>(part, prob, seg, ign, offs, wkeys, skeys);
  kwsum<<<dim3(NCLS, NWP), 256, 0, stream>>>(fw, wkeys, wcnt, wsum);
  k2_topk<<<NCLS * NPART + NCLS, 256, 0, stream>>>(wkeys, skeys, wcnt, scnt,
                                                   psel, idxw, kwv, nwv);
  k2m_merge<<<NCLS, 256, 0, stream>>>(psel, scnt, idxs, ksv, nsv);
  k3a_gather<<<dim3(KSEL + 16, NCLS), 256, 0, stream>>>(fw, fs, idxw, idxs, kwv, ksv,
                                                        dw_dense, ds_dense);
  k3b_loss<<<NCLS, 256, 0, stream>>>(dw_dense, ds_dense, kwv, ksv, nwv, nsv,
                                     simsum, countk);
  k4_final<<<NCLS, 256, 0, stream>>>(mb, wsum, nwv, simsum, countk, out);
}

// Round 5
// 462.011 us; speedup vs baseline: 1.0525x; 1.0525x over previous
//
#include <hip/hip_runtime.h>
#include <stdint.h>

#define NCLS  21
#define CDIM  256
#define HWSZ  16384
#define NPIX  131072
#define EPSV  1e-6f
#define NEGV  -1e30f
#define CAP_W 4096
#define CAP_S 16384
#define KSEL  256
#define NPART 8            // strong top-k partitions per class
#define NWP   16           // wsum pixel partitions per class
#define NBLK  128          // histogram blocks (1024 px each)
#define NGRP  2048         // 64-px groups
#define GPX   64           // pixels per group

__device__ __forceinline__ uint64_t pack_key(float v, unsigned idx) {
  unsigned u = __float_as_uint(v);
  u = (u & 0x80000000u) ? ~u : (u | 0x80000000u);  // order-preserving map
  return ((uint64_t)(~u) << 32) | (uint64_t)idx;   // ascending key == descending value, tie -> low idx
}

// ---------------- KC: per-64px-group histograms + local scan; blocks >=NBLK do proto init ----------------
__global__ void kcount(const int* __restrict__ seg, const int* __restrict__ ign,
                       const float* __restrict__ prob, const float* __restrict__ mb,
                       int* goff, int* btot, float* pn, float* wsum) {
  int t = threadIdx.x;
  if (blockIdx.x >= NBLK) {
    // prototype normalize + wsum zero (former k0), one block per class
    int k = blockIdx.x - NBLK;
    float v = mb[k * CDIM + t];
    float s = v * v;
    for (int o = 32; o > 0; o >>= 1) s += __shfl_down(s, o, 64);
    __shared__ float wsh[4];
    int wid = t >> 6, lane = t & 63;
    if (lane == 0) wsh[wid] = s;
    __syncthreads();
    float tot = wsh[0] + wsh[1] + wsh[2] + wsh[3];
    float inv = 1.0f / fmaxf(sqrtf(tot), EPSV);
    pn[k * CDIM + t] = v * inv;
    wsum[k * CDIM + t] = 0.0f;
    return;
  }
  __shared__ int h[2][16][NCLS];
  int pg = blockIdx.x;
  for (int i = t; i < 2 * 16 * NCLS; i += 256) ((int*)h)[i] = 0;
  __syncthreads();
  int n0 = pg * 1024 + t * 4;
  int g16 = t >> 4;  // 64-px subgroup of this thread's 4 pixels
  int4   sg = *(const int4*)(seg + n0);
  int4   ig = *(const int4*)(ign + n0);
  float4 pr = *(const float4*)(prob + n0);
  if (ig.x != 255) { atomicAdd(&h[0][g16][sg.x], 1); if (pr.x > 0.95f) atomicAdd(&h[1][g16][sg.x], 1); }
  if (ig.y != 255) { atomicAdd(&h[0][g16][sg.y], 1); if (pr.y > 0.95f) atomicAdd(&h[1][g16][sg.y], 1); }
  if (ig.z != 255) { atomicAdd(&h[0][g16][sg.z], 1); if (pr.z > 0.95f) atomicAdd(&h[1][g16][sg.z], 1); }
  if (ig.w != 255) { atomicAdd(&h[0][g16][sg.w], 1); if (pr.w > 0.95f) atomicAdd(&h[1][g16][sg.w], 1); }
  __syncthreads();
  if (t < 2 * NCLS) {
    int typ = t / NCLS, q = t - typ * NCLS;
    int run = 0;
    for (int g = 0; g < 16; ++g) {
      goff[((size_t)typ * NGRP + pg * 16 + g) * NCLS + q] = run;
      run += h[typ][g][q];
    }
    btot[((size_t)typ * NBLK + pg) * NCLS + q] = run;
  }
}

// ---------------- KS: scan the 128 block totals -> per-block bases + class totals ----------------
__global__ void ks_scan(const int* __restrict__ btot, int* bbase, int* scnt, int* wcnt) {
  __shared__ int B[2 * NBLK * NCLS];
  int t = threadIdx.x;
  for (int i = t; i < 2 * NBLK * NCLS; i += 256) B[i] = btot[i];
  __syncthreads();
  if (t < 2 * NCLS) {
    int typ = t / NCLS, q = t - typ * NCLS;
    int run = 0;
    for (int b = 0; b < NBLK; ++b) {
      int idx = (typ * NBLK + b) * NCLS + q;
      bbase[idx] = run;
      run += B[idx];
    }
    if (typ == 0) scnt[q] = run; else wcnt[q] = run;
  }
}

// ---------------- K1F: fused stream + sims + key writes ----------------
// grid NGRP blocks of 256 thr; thread = (cs channel-slice 0..15, pq pixel-quad 0..15)
__global__ void k1f(const float* __restrict__ fw, const float* __restrict__ fs,
                    const float* __restrict__ prob, const int* __restrict__ seg,
                    const int* __restrict__ ign, const float* __restrict__ pn,
                    const int* __restrict__ goff, const int* __restrict__ bbase,
                    uint64_t* wkeys, uint64_t* skeys) {
  __shared__ float pnT[CDIM * NCLS];   // [c][q], 21.5 KB
  __shared__ float red[16 * 256];      // [cs][px*4+qty], 16 KB
  __shared__ float red2[256];
  __shared__ int ls[NCLS], lw[NCLS];
  __shared__ int segs[GPX];
  __shared__ unsigned char fval[GPX], fcf[GPX];
  int t = threadIdx.x;
  int g = blockIdx.x;
  int px0 = g * GPX;
  int cs = t >> 4, pq = t & 15;
  for (int i = t; i < CDIM * NCLS; i += 256) {
    int c = i / NCLS, q = i - c * NCLS;
    pnT[i] = pn[q * CDIM + c];
  }
  if (t < NCLS) {
    ls[t] = bbase[(g >> 4) * NCLS + t] + goff[(size_t)g * NCLS + t];
    lw[t] = bbase[(NBLK + (g >> 4)) * NCLS + t] + goff[((size_t)NGRP + g) * NCLS + t];
  }
  if (t < GPX) {
    int n = px0 + t;
    int iv = ign[n];
    segs[t] = seg[n];
    float pv = prob[n];
    bool val = (iv != 255);
    fval[t] = val ? 1 : 0;
    fcf[t] = (val && pv > 0.95f) ? 1 : 0;
  }
  __syncthreads();
  int b = px0 >> 14;
  int hw0 = (px0 & (HWSZ - 1)) + pq * 4;
  int ch0 = cs * 16;
  int s0 = segs[pq * 4 + 0], s1 = segs[pq * 4 + 1];
  int s2 = segs[pq * 4 + 2], s3 = segs[pq * 4 + 3];
  const float* fwp = fw + ((size_t)(b * CDIM + ch0)) * HWSZ + hw0;
  const float* fsp = fs + ((size_t)(b * CDIM + ch0)) * HWSZ + hw0;
  float4 dwv = {0,0,0,0}, nwv = {0,0,0,0}, dsv = {0,0,0,0}, nsv = {0,0,0,0};
#pragma unroll
  for (int cl = 0; cl < 16; cl += 4) {
    float4 A[4], S[4];
#pragma unroll
    for (int j = 0; j < 4; ++j) {
      A[j] = *(const float4*)(fwp + (size_t)(cl + j) * HWSZ);
      S[j] = *(const float4*)(fsp + (size_t)(cl + j) * HWSZ);
    }
#pragma unroll
    for (int j = 0; j < 4; ++j) {
      int cb = (ch0 + cl + j) * NCLS;
      float p0 = pnT[cb + s0], p1 = pnT[cb + s1], p2 = pnT[cb + s2], p3 = pnT[cb + s3];
      dwv.x = fmaf(A[j].x, p0, dwv.x); nwv.x = fmaf(A[j].x, A[j].x, nwv.x);
      dwv.y = fmaf(A[j].y, p1, dwv.y); nwv.y = fmaf(A[j].y, A[j].y, nwv.y);
      dwv.z = fmaf(A[j].z, p2, dwv.z); nwv.z = fmaf(A[j].z, A[j].z, nwv.z);
      dwv.w = fmaf(A[j].w, p3, dwv.w); nwv.w = fmaf(A[j].w, A[j].w, nwv.w);
      dsv.x = fmaf(S[j].x, p0, dsv.x); nsv.x = fmaf(S[j].x, S[j].x, nsv.x);
      dsv.y = fmaf(S[j].y, p1, dsv.y); nsv.y = fmaf(S[j].y, S[j].y, nsv.y);
      dsv.z = fmaf(S[j].z, p2, dsv.z); nsv.z = fmaf(S[j].z, S[j].z, nsv.z);
      dsv.w = fmaf(S[j].w, p3, dsv.w); nsv.w = fmaf(S[j].w, S[j].w, nsv.w);
    }
  }
  int rb = cs * 256 + pq * 16;
  red[rb +  0] = dwv.x; red[rb +  1] = nwv.x; red[rb +  2] = dsv.x; red[rb +  3] = nsv.x;
  red[rb +  4] = dwv.y; red[rb +  5] = nwv.y; red[rb +  6] = dsv.y; red[rb +  7] = nsv.y;
  red[rb +  8] = dwv.z; red[rb +  9] = nwv.z; red[rb + 10] = dsv.z; red[rb + 11] = nsv.z;
  red[rb + 12] = dwv.w; red[rb + 13] = nwv.w; red[rb + 14] = dsv.w; red[rb + 15] = nsv.w;
  __syncthreads();
  float ssum = 0.0f;
#pragma unroll
  for (int c2 = 0; c2 < 16; ++c2) ssum += red[c2 * 256 + t];
  red2[t] = ssum;
  __syncthreads();
  if (t < GPX && fval[t]) {
    float dw = red2[t * 4 + 0], nw = red2[t * 4 + 1];
    float ds = red2[t * 4 + 2], ns = red2[t * 4 + 3];
    int q = segs[t];
    unsigned n = (unsigned)(px0 + t);
    float sim_s = ds / fmaxf(sqrtf(ns), EPSV);
    int pos = atomicAdd(&ls[q], 1);
    if (pos < CAP_S) skeys[(size_t)q * CAP_S + pos] = pack_key(-sim_s, n);
    if (fcf[t]) {
      float sim_w = dw / fmaxf(sqrtf(nw), EPSV);
      int pw = atomicAdd(&lw[q], 1);
      if (pw < CAP_W) wkeys[(size_t)q * CAP_W + pw] = pack_key(sim_w, n);
    }
  }
}

// ---------------- KW: wsum via weak-candidate list replay (batched gather) ----------------
__global__ void kwsum(const float* __restrict__ fw, const uint64_t* __restrict__ wkeys,
                      const int* __restrict__ wcnt, float* wsum) {
  int q = blockIdx.x, p = blockIdx.y, t = threadIdx.x;
  int cnt = min(wcnt[q], CAP_W);
  int chunk = (cnt + NWP - 1) / NWP;
  int lo = p * chunk, hi = min(lo + chunk, cnt);
  float acc = 0.0f;
  int i = lo;
  for (; i + 4 <= hi; i += 4) {
    float v[4];
#pragma unroll
    for (int j = 0; j < 4; ++j) {
      unsigned n = (unsigned)(wkeys[(size_t)q * CAP_W + i + j] & 0xFFFFFFFFull);
      int b = (int)(n >> 14), hw = (int)(n & (HWSZ - 1));
      v[j] = fw[((size_t)(b * CDIM + t)) * HWSZ + hw];
    }
    acc += (v[0] + v[1]) + (v[2] + v[3]);
  }
  for (; i < hi; ++i) {
    unsigned n = (unsigned)(wkeys[(size_t)q * CAP_W + i] & 0xFFFFFFFFull);
    int b = (int)(n >> 14), hw = (int)(n & (HWSZ - 1));
    acc += fw[((size_t)(b * CDIM + t)) * HWSZ + hw];
  }
  if (hi > lo) atomicAdd(&wsum[q * CDIM + t], acc);
}

// ---------------- top-256 select (cutoff-filtered bitonic), 256 threads ----------------
__device__ void select_topk(const uint64_t* __restrict__ list, int cnt,
                            uint64_t* T, uint64_t* P, int* pcnt, int* woff) {
  int t = threadIdx.x;
  T[t] = ~0ull;
  if (t == 0) *pcnt = 0;
  __syncthreads();
  for (int base = 0; base < cnt; base += 256) {
    uint64_t key = (base + t < cnt) ? list[base + t] : ~0ull;
    uint64_t cutoff = T[KSEL - 1];
    bool pred = key < cutoff;
    unsigned long long mask = __ballot(pred);
    int wid = t >> 6, lane = t & 63;
    if (lane == 0) woff[wid] = __popcll(mask);
    int prefix = __popcll(mask & ((1ull << lane) - 1ull));
    __syncthreads();
    int off = 0;
    for (int w2 = 0; w2 < wid; ++w2) off += woff[w2];
    int total = woff[0] + woff[1] + woff[2] + woff[3];
    int old = *pcnt;
    if (pred) P[old + off + prefix] = key;
    int newc = old + total;
    __syncthreads();
    if (t == 0) *pcnt = newc;
    bool last = (base + 256 >= cnt);
    if (newc >= KSEL || (last && newc > 0)) {
      for (int i2 = t; i2 < 2 * KSEL; i2 += 256)
        if (i2 >= newc) P[i2] = ~0ull;
      for (unsigned size = 2; size <= 2 * KSEL; size <<= 1) {
        for (unsigned stride = size >> 1; stride > 0; stride >>= 1) {
          __syncthreads();
          unsigned lo = stride - 1;
          unsigned i = (((unsigned)t & ~lo) << 1) | ((unsigned)t & lo);
          unsigned j = i | stride;
          uint64_t a = P[i], b = P[j];
          bool up = ((i & size) == 0);
          if ((a > b) == up) { P[i] = b; P[j] = a; }
        }
      }
      __syncthreads();
      uint64_t a = T[t], b = P[KSEL - 1 - t];
      T[t] = a < b ? a : b;
      for (unsigned stride = KSEL / 2; stride > 0; stride >>= 1) {
        __syncthreads();
        if (((unsigned)t & stride) == 0) {
          uint64_t x = T[t], y = T[t + stride];
          if (x > y) { T[t] = y; T[t + stride] = x; }
        }
      }
      __syncthreads();
      if (t == 0) *pcnt = 0;
      __syncthreads();
    } else {
      __syncthreads();
    }
  }
}

// ---------------- K2: weak top-16 (full) + strong top-256 (partitioned) ----------------
__global__ void k2_topk(const uint64_t* __restrict__ wkeys, const uint64_t* __restrict__ skeys,
                        const int* wcnt, const int* scnt,
                        uint64_t* psel, int* idxw, int* kwv, int* nwv) {
  __shared__ uint64_t T[KSEL];
  __shared__ uint64_t P[2 * KSEL];
  __shared__ int pcnt;
  __shared__ int woff[4];
  int bid = blockIdx.x, t = threadIdx.x;
  if (bid < NCLS * NPART) {
    int k = bid / NPART, p = bid % NPART;
    int cnt = min(scnt[k], CAP_S);
    int chunk = (cnt + NPART - 1) / NPART;
    int lo = p * chunk;
    int hi = min(lo + chunk, cnt);
    int c = hi > lo ? hi - lo : 0;
    select_topk(skeys + (size_t)k * CAP_S + lo, c, T, P, &pcnt, woff);
    psel[((size_t)k * NPART + p) * KSEL + t] = T[t];
  } else {
    int k = bid - NCLS * NPART;
    int cnt_total = wcnt[k];
    int cnt = min(cnt_total, CAP_W);
    select_topk(wkeys + (size_t)k * CAP_W, cnt, T, P, &pcnt, woff);
    if (t < 16) idxw[k * 16 + t] = (int)(unsigned)(T[t] & 0xFFFFFFFFull);
    if (t == 0) { nwv[k] = cnt_total; kwv[k] = min(cnt_total, 16); }
  }
}

// ---------------- K2m: merge 8 sorted partition results -> final strong top-256 ----------------
__global__ void k2m_merge(const uint64_t* __restrict__ psel, const int* scnt,
                          int* idxs, int* ksv, int* nsv) {
  int k = blockIdx.x, t = threadIdx.x;
  __shared__ uint64_t M[NPART * KSEL];  // 2048
  for (int i = t; i < NPART * KSEL; i += 256) M[i] = psel[(size_t)k * NPART * KSEL + i];
  for (unsigned size = 2; size <= NPART * KSEL; size <<= 1) {
    for (unsigned stride = size >> 1; stride > 0; stride >>= 1) {
      __syncthreads();
      for (unsigned q = t; q < NPART * KSEL / 2; q += 256) {
        unsigned lo = stride - 1;
        unsigned i = ((q & ~lo) << 1) | (q & lo);
        unsigned j = i | stride;
        uint64_t a = M[i], b = M[j];
        bool up = ((i & size) == 0);
        if ((a > b) == up) { M[i] = b; M[j] = a; }
      }
    }
  }
  __syncthreads();
  idxs[k * KSEL + t] = (int)(unsigned)(M[t] & 0xFFFFFFFFull);
  if (t == 0) { int c = scnt[k]; nsv[k] = c; ksv[k] = c < KSEL ? c : KSEL; }
}

// ---------------- K3a: gather + normalize selected vectors into dense buffers ----------------
__global__ void k3a_gather(const float* __restrict__ fw, const float* __restrict__ fs,
                           const int* __restrict__ idxw, const int* __restrict__ idxs,
                           const int* __restrict__ kwv, const int* __restrict__ ksv,
                           float* dw_dense, float* ds_dense) {
  int k = blockIdx.y;
  int slot = blockIdx.x;  // 0..255 strong, 256..271 weak
  int t = threadIdx.x;
  bool strong = slot < KSEL;
  float v = 0.0f;
  int n = 0;
  bool ok;
  if (strong) {
    ok = slot < ksv[k];
    if (ok) n = idxs[k * KSEL + slot];
  } else {
    int i = slot - KSEL;
    ok = i < kwv[k];
    int rank = i > 0 ? i - 1 : 0;  // ranks = max(arange(16)-1, 0)
    if (ok) n = idxw[k * 16 + rank];
  }
  if (ok) {
    int b = n >> 14, hw = n & (HWSZ - 1);
    const float* f = strong ? fs : fw;
    v = f[(size_t)(b * CDIM + t) * HWSZ + hw];
  }
  float s = v * v;
  for (int o = 32; o > 0; o >>= 1) s += __shfl_down(s, o, 64);
  __shared__ float wsh[4];
  int wid = t >> 6, lane = t & 63;
  if (lane == 0) wsh[wid] = s;
  __syncthreads();
  float tot = wsh[0] + wsh[1] + wsh[2] + wsh[3];
  float inv = 1.0f / fmaxf(sqrtf(tot), EPSV);
  float out = v * inv;
  if (strong) ds_dense[((size_t)k * KSEL + slot) * CDIM + t] = out;
  else        dw_dense[((size_t)k * 16 + (slot - KSEL)) * CDIM + t] = out;
}

// ---------------- K3b: cosm, per-row max, per-class sum ----------------
__global__ void k3b_loss(const float* __restrict__ dw_dense, const float* __restrict__ ds_dense,
                         const int* kwv, const int* ksv, const int* nwv, const int* nsv,
                         float* simsum, int* countk) {
  int k = blockIdx.x, t = threadIdx.x;
  int wid = t >> 6, lane = t & 63;
  __shared__ float wn[16 * CDIM];
  __shared__ float wred[4][16];
  for (int i = t; i < 16 * CDIM; i += 256) wn[i] = dw_dense[(size_t)k * 16 * CDIM + i];
  __syncthreads();
  int ks_ = ksv[k], kw_ = kwv[k];
  bool ok = (nwv[k] > 0) && (nsv[k] > 0);
  float dots[16];
#pragma unroll
  for (int i = 0; i < 16; ++i) dots[i] = 0.0f;
  bool jv = ok && (t < ks_);
  if (jv) {
    const float4* sp = (const float4*)(ds_dense + ((size_t)k * KSEL + t) * CDIM);
    for (int c4 = 0; c4 < CDIM / 4; ++c4) {
      float4 v = sp[c4];
#pragma unroll
      for (int i = 0; i < 16; ++i) {
        float4 w = ((const float4*)(wn + i * CDIM))[c4];
        dots[i] = fmaf(v.x, w.x, dots[i]);
        dots[i] = fmaf(v.y, w.y, dots[i]);
        dots[i] = fmaf(v.z, w.z, dots[i]);
        dots[i] = fmaf(v.w, w.w, dots[i]);
      }
    }
  }
#pragma unroll
  for (int i = 0; i < 16; ++i) {
    float v = jv ? dots[i] : NEGV;
    for (int o = 32; o > 0; o >>= 1) v = fmaxf(v, __shfl_down(v, o, 64));
    if (lane == 0) wred[wid][i] = v;
  }
  __syncthreads();
  if (t == 0) {
    float csum = 0.0f;
    for (int i = 0; i < kw_; ++i) {
      float m = fmaxf(fmaxf(wred[0][i], wred[1][i]), fmaxf(wred[2][i], wred[3][i]));
      csum += m;
    }
    simsum[k] = ok ? csum : 0.0f;
    countk[k] = ok ? ks_ : 0;
  }
}

// ---------------- K4: memory bank update + loss ----------------
__global__ void k4_final(const float* __restrict__ mb, const float* __restrict__ wsum,
                         const int* __restrict__ nwv, const float* __restrict__ simsum,
                         const int* __restrict__ countk, float* out) {
  int k = blockIdx.x, t = threadIdx.x;
  float p = mb[k * CDIM + t];
  float o = p;
  int nw = nwv[k];
  if (nw > 0) {
    float mean = wsum[k * CDIM + t] / (float)nw;
    o = 0.99f * p + 0.01f * mean;
  }
  out[1 + k * CDIM + t] = o;
  if (k == 0 && t == 0) {
    float ss = 0.0f;
    int cc = 0;
    for (int q = 0; q < NCLS; ++q) { ss += simsum[q]; cc += countk[q]; }
    out[0] = (cc > 0) ? (1.0f - ss / (float)cc) : 0.0f;
  }
}

extern "C" void kernel_launch(void* const* d_in, const int* in_sizes, int n_in,
                              void* d_out, int out_size, void* d_ws, size_t ws_size,
                              hipStream_t stream) {
  const float* fw   = (const float*)d_in[0];
  const float* fs   = (const float*)d_in[1];
  const float* prob = (const float*)d_in[2];
  const float* mb   = (const float*)d_in[3];
  const int*   seg  = (const int*)d_in[4];
  const int*   ign  = (const int*)d_in[5];
  float* out = (float*)d_out;

  char* ws = (char*)d_ws;
  size_t off = 0;
  auto alloc = [&](size_t bytes) -> char* {
    char* p = ws + off;
    off = (off + bytes + 255) & ~(size_t)255;
    return p;
  };
  float*    pn       = (float*)alloc(NCLS * CDIM * 4);
  float*    wsum     = (float*)alloc(NCLS * CDIM * 4);
  int*      wcnt     = (int*)alloc(NCLS * 4);
  int*      scnt     = (int*)alloc(NCLS * 4);
  int*      idxw     = (int*)alloc(NCLS * 16 * 4);
  int*      idxs     = (int*)alloc(NCLS * KSEL * 4);
  int*      kwv      = (int*)alloc(NCLS * 4);
  int*      ksv      = (int*)alloc(NCLS * 4);
  int*      nwv      = (int*)alloc(NCLS * 4);
  int*      nsv      = (int*)alloc(NCLS * 4);
  float*    simsum   = (float*)alloc(NCLS * 4);
  int*      countk   = (int*)alloc(NCLS * 4);
  int*      goff     = (int*)alloc((size_t)2 * NGRP * NCLS * 4);
  int*      btot     = (int*)alloc((size_t)2 * NBLK * NCLS * 4);
  int*      bbase    = (int*)alloc((size_t)2 * NBLK * NCLS * 4);
  uint64_t* wkeys    = (uint64_t*)alloc((size_t)NCLS * CAP_W * 8);
  uint64_t* skeys    = (uint64_t*)alloc((size_t)NCLS * CAP_S * 8);
  uint64_t* psel     = (uint64_t*)alloc((size_t)NCLS * NPART * KSEL * 8);
  float*    dw_dense = (float*)alloc((size_t)NCLS * 16 * CDIM * 4);
  float*    ds_dense = (float*)alloc((size_t)NCLS * KSEL * CDIM * 4);
  (void)in_sizes; (void)n_in; (void)out_size; (void)ws_size;

  kcount<<<NBLK + NCLS, 256, 0, stream>>>(seg, ign, prob, mb, goff, btot, pn, wsum);
  ks_scan<<<1, 256, 0, stream>>>(btot, bbase, scnt, wcnt);
  k1f<<<NGRP, 256, 0, stream>>>(fw, fs, prob, seg, ign, pn, goff, bbase, wkeys, skeys);
  kwsum<<<dim3(NCLS, NWP), 256, 0, stream>>>(fw, wkeys, wcnt, wsum);
  k2_topk<<<NCLS * NPART + NCLS, 256, 0, stream>>>(wkeys, skeys, wcnt, scnt,
                                                   psel, idxw, kwv, nwv);
  k2m_merge<<<NCLS, 256, 0, stream>>>(psel, scnt, idxs, ksv, nsv);
  k3a_gather<<<dim3(KSEL + 16, NCLS), 256, 0, stream>>>(fw, fs, idxw, idxs, kwv, ksv,
                                                        dw_dense, ds_dense);
  k3b_loss<<<NCLS, 256, 0, stream>>>(dw_dense, ds_dense, kwv, ksv, nwv, nsv,
                                     simsum, countk);
  k4_final<<<NCLS, 256, 0, stream>>>(mb, wsum, nwv, simsum, countk, out);
}